// Round 2
// 327.678 us; speedup vs baseline: 1.0231x; 1.0231x over previous
//
#include <hip/hip_runtime.h>

#define NN 100000
#define NE 1600000
#define HF 128
#define NC 64
#define AP 136      // padded LDS row (bf16 elems): 272B stride, 16B-aligned chunks
#define NB 391      // edge buckets: ceil(100000/256)
#define BSH 8       // 256 nodes per bucket
#define BMASK 255
#define BCAP 4608   // fixed bucket capacity (mean 4096 + 8 sigma)

typedef __bf16 bf16x8 __attribute__((ext_vector_type(8)));
typedef float  f32x4  __attribute__((ext_vector_type(4)));
typedef float  f32x2  __attribute__((ext_vector_type(2)));
typedef unsigned short us8 __attribute__((ext_vector_type(8)));
typedef unsigned int u32x4 __attribute__((ext_vector_type(4)));

__device__ __forceinline__ unsigned short f2b(float x) {
  unsigned int u = __float_as_uint(x);
  u += 0x7FFFu + ((u >> 16) & 1u);   // RNE
  return (unsigned short)(u >> 16);
}
__device__ __forceinline__ float b2f(unsigned short b) {
  return __uint_as_float(((unsigned int)b) << 16);
}

// accumulate one 16B chunk (8 bf16) into 4 float2 accumulators via pk_add
__device__ __forceinline__ void addrow(f32x2 acc[4], u32x4 w) {
  #pragma unroll
  for (int i = 0; i < 4; i++) {
    f32x2 p;
    p.x = __uint_as_float(w[i] << 16);          // even element
    p.y = __uint_as_float(w[i] & 0xFFFF0000u);  // odd element
    acc[i] += p;                                 // v_pk_add_f32
  }
}

// ---------------- prologue_bin: cast x->bf16, swizzle weights, init gcur,
//                  AND (blocks < NB) bin edges into fixed-capacity buckets ----
// wt layout (ushort):  ((((ls)*4 + k0)*8 + nt)*64 + q*16 + m)*8 + j
// wtf layout (ushort): (((k0)*4 + nt)*64 + q*16 + m)*8 + j
// binned entry = src (17 bits) | dst_local (8 bits) << 17
__global__ __launch_bounds__(512) void prologue_bin(const float* __restrict__ x,
                                                    unsigned short* __restrict__ xb,
                                                    const float* __restrict__ conv_w,
                                                    const float* __restrict__ conv_b,
                                                    const float* __restrict__ bn_g,
                                                    const float* __restrict__ bn_b,
                                                    const float* __restrict__ bn_m,
                                                    const float* __restrict__ bn_v,
                                                    const float* __restrict__ fc_w,
                                                    unsigned short* __restrict__ wt,
                                                    unsigned short* __restrict__ wtf,
                                                    float* __restrict__ sarr,
                                                    float* __restrict__ tarr,
                                                    int* __restrict__ gcur,
                                                    const int* __restrict__ src,
                                                    const int* __restrict__ dst,
                                                    unsigned int* __restrict__ binned) {
  __shared__ int hist[NB];
  int t = threadIdx.x;
  int idx = blockIdx.x * 512 + t;                 // grid 3125*512 = 1.6M
  // ---- cast: 12.8M floats, 8 per thread ----
  {
    size_t i = (size_t)idx * 8;
    float4 a = *(const float4*)(x + i);
    float4 b = *(const float4*)(x + i + 4);
    us8 v = { f2b(a.x), f2b(a.y), f2b(a.z), f2b(a.w),
              f2b(b.x), f2b(b.y), f2b(b.z), f2b(b.w) };
    *(us8*)(xb + i) = v;
  }
  // ---- zero row NN of the three activation buffers (gather pad target) ----
  if (idx < 3 * HF) {
    int k = idx >> 7, jj = idx & 127;
    xb[(size_t)k * (NN + 1) * HF + (size_t)NN * HF + jj] = 0;
  }
  // ---- weight swizzle + BN fold ----
  if (idx < 6 * HF * HF) {
    int j  = idx & 7;
    int m  = (idx >> 3) & 15;
    int q  = (idx >> 7) & 3;
    int nt = (idx >> 9) & 7;
    int k0 = (idx >> 12) & 3;
    int ls = idx >> 14;                 // 0..5
    int k = k0 * 32 + q * 8 + j;
    int n = nt * 16 + m;
    wt[idx] = f2b(conv_w[(ls * HF + k) * HF + n]);
  }
  if (idx < HF * NC) {
    int j  = idx & 7;
    int m  = (idx >> 3) & 15;
    int q  = (idx >> 7) & 3;
    int nt = (idx >> 9) & 3;
    int k0 = idx >> 11;                 // 0..3
    int k = k0 * 32 + q * 8 + j;
    int c = nt * 16 + m;
    wtf[idx] = f2b(fc_w[k * NC + c]);
  }
  if (idx < 6 * HF) {
    float s = bn_g[idx] * rsqrtf(bn_v[idx] + 1e-5f);
    sarr[idx] = s;
    tarr[idx] = (conv_b[idx] - bn_m[idx]) * s + bn_b[idx];
  }
  // ---- bin edges (blocks 0..NB-1); gcur holds per-bucket running count,
  //      memset to 0 by host before this kernel ----
  if (blockIdx.x < NB) {
    if (t < NB) hist[t] = 0;
    __syncthreads();
    int base = blockIdx.x * 4096;
    int sv[8], dv[8];
    #pragma unroll
    for (int j = 0; j < 8; j++) {
      int e = base + j * 512 + t;
      bool ok = e < NE;
      dv[j] = ok ? dst[e] : -1;
      sv[j] = ok ? src[e] : 0;
      if (ok) atomicAdd(&hist[dv[j] >> BSH], 1);
    }
    __syncthreads();
    if (t < NB) {
      int c = hist[t];
      if (c) hist[t] = t * BCAP + atomicAdd(&gcur[t], c);
    }
    __syncthreads();
    #pragma unroll
    for (int j = 0; j < 8; j++) {
      if (dv[j] >= 0) {
        int b = dv[j] >> BSH;
        int p = atomicAdd(&hist[b], 1);
        binned[p] = (unsigned int)sv[j] | ((unsigned int)(dv[j] & BMASK) << 17);
      }
    }
  }
}

// ---------------- per-bucket CSR build: offs + deg + csr (L2-local scatter) ----
__global__ __launch_bounds__(512) void build_csr(const unsigned int* __restrict__ binned,
                                                 const int* __restrict__ gcur,
                                                 int* __restrict__ offs,
                                                 int* __restrict__ deg,
                                                 int* __restrict__ csr) {
  __shared__ int ncnt[256];
  __shared__ int sm[256];
  int t = threadIdx.x;
  int b = blockIdx.x;
  int beg = b * BCAP;
  int cntb = gcur[b];                       // gcur holds per-bucket edge count
  if (t < 256) ncnt[t] = 0;
  __syncthreads();
  for (int e = beg + t; e < beg + cntb; e += 512) atomicAdd(&ncnt[binned[e] >> 17], 1);
  __syncthreads();
  int s = 0;
  if (t < 256) { s = ncnt[t]; sm[t] = s; }
  __syncthreads();
  for (int off = 1; off < 256; off <<= 1) {
    int u = (t < 256 && t >= off) ? sm[t - off] : 0;
    __syncthreads();
    if (t < 256) sm[t] += u;
    __syncthreads();
  }
  if (t < 256) {
    int ex = sm[t] - s + beg;
    int node = (b << BSH) + t;
    if (node < NN) { offs[node] = ex; deg[node] = s; }
    ncnt[t] = ex;
  }
  __syncthreads();
  for (int e = beg + t; e < beg + cntb; e += 512) {
    unsigned int u = binned[e];
    int p = atomicAdd(&ncnt[u >> 17], 1);
    csr[p] = (int)(u & 0x1FFFFu);
  }
}

// ---------------- aggregation: hsum[i] = h[i] + sum_{e->i} h[src_e]  (bf16) ----
// Round-8 form: one coalesced csr load per wave (64 indices in registers),
// gather addresses via ds_bpermute shuffles -> 4-deep independent load
// pipeline; packed f32x2 accumulate (v_pk_add_f32). Lanes past the degree
// gather the dedicated zero row at index NN.
__global__ __launch_bounds__(256) void aggregate(const unsigned short* __restrict__ h,
                                                 const int* __restrict__ offs,
                                                 const int* __restrict__ deg,
                                                 const int* __restrict__ csr,
                                                 unsigned short* __restrict__ out) {
  int wave = threadIdx.x >> 6;
  int lane = threadIdx.x & 63;
  int node = blockIdx.x * 4 + wave;
  int g  = lane >> 4;     // edge stream 0..3
  int sl = lane & 15;     // 16B column chunk
  int beg = offs[node];
  int dg  = deg[node];
  int n  = dg + 1;        // edges + self
  int nf = n < 64 ? n : 64;

  // coalesced neighbor-index fetch: lane i holds edge i (lane dg = self row)
  int myidx = NN;                                   // zero row pad
  if (lane < nf) myidx = (lane == dg) ? node : csr[beg + lane];

  f32x2 acc[4];
  #pragma unroll
  for (int i = 0; i < 4; i++) acc[i] = (f32x2){0.f, 0.f};

  int K = (nf + 3) >> 2;     // quad-iterations (4 rows per iteration, one/stream)
  int j = 0;
  for (; j + 3 < K; j += 4) {          // 4 independent gathers in flight
    int s0 = __shfl(myidx, (j + 0) * 4 + g);
    int s1 = __shfl(myidx, (j + 1) * 4 + g);
    int s2 = __shfl(myidx, (j + 2) * 4 + g);
    int s3 = __shfl(myidx, (j + 3) * 4 + g);
    u32x4 v0 = *(const u32x4*)(h + (size_t)s0 * HF + sl * 8);
    u32x4 v1 = *(const u32x4*)(h + (size_t)s1 * HF + sl * 8);
    u32x4 v2 = *(const u32x4*)(h + (size_t)s2 * HF + sl * 8);
    u32x4 v3 = *(const u32x4*)(h + (size_t)s3 * HF + sl * 8);
    addrow(acc, v0);
    addrow(acc, v1);
    addrow(acc, v2);
    addrow(acc, v3);
  }
  for (; j + 1 < K; j += 2) {
    int s0 = __shfl(myidx, (j + 0) * 4 + g);
    int s1 = __shfl(myidx, (j + 1) * 4 + g);
    u32x4 v0 = *(const u32x4*)(h + (size_t)s0 * HF + sl * 8);
    u32x4 v1 = *(const u32x4*)(h + (size_t)s1 * HF + sl * 8);
    addrow(acc, v0);
    addrow(acc, v1);
  }
  if (j < K) {
    int s0 = __shfl(myidx, j * 4 + g);
    u32x4 v0 = *(const u32x4*)(h + (size_t)s0 * HF + sl * 8);
    addrow(acc, v0);
  }

  // rare tail: degree >= 64 (statistically absent at lambda=16, kept for safety)
  if (dg >= 64) {
    for (int e = beg + 64 + g; e < beg + dg; e += 4) {
      int s = csr[e];
      u32x4 v = *(const u32x4*)(h + (size_t)s * HF + sl * 8);
      addrow(acc, v);
    }
    if (g == 0) {   // self row wasn't covered by the lane==dg slot
      u32x4 v = *(const u32x4*)(h + (size_t)node * HF + sl * 8);
      addrow(acc, v);
    }
  }

  // cross-stream reduce (4 partial sums per column chunk)
  #pragma unroll
  for (int i = 0; i < 4; i++) {
    acc[i].x += __shfl_xor(acc[i].x, 16, 64);
    acc[i].y += __shfl_xor(acc[i].y, 16, 64);
    acc[i].x += __shfl_xor(acc[i].x, 32, 64);
    acc[i].y += __shfl_xor(acc[i].y, 32, 64);
  }
  if (g == 0) {
    us8 r;
    #pragma unroll
    for (int i = 0; i < 4; i++) {
      r[2 * i]     = f2b(acc[i].x);
      r[2 * i + 1] = f2b(acc[i].y);
    }
    *(us8*)(out + (size_t)node * HF + sl * 8) = r;
  }
}

// =======================================================================
// Barrier-free MLP (16 rows/wave, round-7 form): weights direct from global
// (fragment-swizzled, L1/L2-resident); activations wave-private.
// =======================================================================
__device__ __forceinline__ void mlp3_body(const unsigned short* __restrict__ in,
                                          unsigned short* Ab,
                                          const unsigned short* __restrict__ wt,
                                          const float* __restrict__ sarr,
                                          const float* __restrict__ tarr,
                                          int layer, int row0, int wave, int lane,
                                          bf16x8 af[4]) {
  int m = lane & 15, q = lane >> 4;
  int node = row0 + wave * 16 + m;
  int nclamp = (node < NN) ? node : 0;        // OOB rows compute garbage, never stored
  #pragma unroll
  for (int k0 = 0; k0 < 4; k0++)
    af[k0] = *(const bf16x8*)(in + (size_t)nclamp * HF + k0 * 32 + q * 8);

  const unsigned short* wbase = wt + layer * 3 * 16384;   // 16384 ushorts per sub
  #pragma unroll
  for (int sub = 0; sub < 3; sub++) {
    const unsigned short* wsub = wbase + sub * 16384;
    f32x4 acc[8];
    #pragma unroll
    for (int nt = 0; nt < 8; nt++) {
      acc[nt] = (f32x4){0.f, 0.f, 0.f, 0.f};
      #pragma unroll
      for (int k0 = 0; k0 < 4; k0++) {
        bf16x8 bf = *(const bf16x8*)(wsub + ((k0 * 8 + nt) * 64 + lane) * 8);
        acc[nt] = __builtin_amdgcn_mfma_f32_16x16x32_bf16(af[k0], bf, acc[nt], 0, 0, 0);
      }
    }
    const float* sp = sarr + (layer * 3 + sub) * HF;
    const float* tp = tarr + (layer * 3 + sub) * HF;
    #pragma unroll
    for (int nt = 0; nt < 8; nt++) {
      int c = nt * 16 + m;
      float sc = sp[c], sh = tp[c];
      #pragma unroll
      for (int i = 0; i < 4; i++) {
        int r = wave * 16 + q * 4 + i;     // C/D: col=lane&15, row=(lane>>4)*4+i
        float y = fmaxf(acc[nt][i] * sc + sh, 0.f);
        Ab[r * AP + c] = f2b(y);           // own rows: no barrier
      }
    }
    #pragma unroll
    for (int k0 = 0; k0 < 4; k0++)         // reload fragments (wave-local LDS RAW)
      af[k0] = *(const bf16x8*)&Ab[(wave * 16 + m) * AP + k0 * 32 + q * 8];
  }
}

// ---------------- layer-0 MLP: bf16 in -> bf16 out ----------------
__global__ __launch_bounds__(256) void mlp3(const unsigned short* __restrict__ in,
                                            unsigned short* __restrict__ out,
                                            const unsigned short* __restrict__ wt,
                                            const float* __restrict__ sarr,
                                            const float* __restrict__ tarr) {
  __shared__ unsigned short Ab[64 * AP];
  int t = threadIdx.x;
  int lane = t & 63, wave = t >> 6;
  int row0 = blockIdx.x * 64;
  bf16x8 af[4];
  mlp3_body(in, Ab, wt, sarr, tarr, 0, row0, wave, lane, af);

  // wave-local coalesced bf16 store of own 16 rows
  for (int it = 0; it < 4; it++) {
    int idx = it * 64 + lane;              // 4 rows x 16 chunks per pass
    int r = wave * 16 + (idx >> 4);
    int c = (idx & 15) << 3;
    int gr = row0 + r;
    if (gr < NN) *(us8*)(out + (size_t)gr * HF + c) = *(const us8*)&Ab[r * AP + c];
  }
}

// ---------------- layer-1 MLP + FC(128->64) + log_softmax ----------------
__global__ __launch_bounds__(256) void mlp3fc(const unsigned short* __restrict__ in,
                                              float* __restrict__ out,
                                              const unsigned short* __restrict__ wt,
                                              const float* __restrict__ sarr,
                                              const float* __restrict__ tarr,
                                              const unsigned short* __restrict__ wtf,
                                              const float* __restrict__ fc_b) {
  __shared__ unsigned short Ab[64 * AP];
  int t = threadIdx.x;
  int lane = t & 63, wave = t >> 6;
  int row0 = blockIdx.x * 64;
  int m = lane & 15, q = lane >> 4;
  bf16x8 af[4];
  mlp3_body(in, Ab, wt, sarr, tarr, 1, row0, wave, lane, af);

  // ---- FC 128->64 + log_softmax, all in registers ----
  f32x4 acc[4];
  #pragma unroll
  for (int nt = 0; nt < 4; nt++) {
    acc[nt] = (f32x4){0.f, 0.f, 0.f, 0.f};
    #pragma unroll
    for (int k0 = 0; k0 < 4; k0++) {
      bf16x8 bf = *(const bf16x8*)(wtf + ((k0 * 4 + nt) * 64 + lane) * 8);
      acc[nt] = __builtin_amdgcn_mfma_f32_16x16x32_bf16(af[k0], bf, acc[nt], 0, 0, 0);
    }
  }
  // logits: lane (q,m) holds rows q*4+i (i<4), cols nt*16+m
  float v[4][4];
  #pragma unroll
  for (int nt = 0; nt < 4; nt++) {
    float b = fc_b[nt * 16 + m];
    #pragma unroll
    for (int i = 0; i < 4; i++) v[nt][i] = acc[nt][i] + b;
  }
  float mx[4], sum[4];
  #pragma unroll
  for (int i = 0; i < 4; i++) {
    mx[i] = fmaxf(fmaxf(v[0][i], v[1][i]), fmaxf(v[2][i], v[3][i]));
    mx[i] = fmaxf(mx[i], __shfl_xor(mx[i], 1, 64));
    mx[i] = fmaxf(mx[i], __shfl_xor(mx[i], 2, 64));
    mx[i] = fmaxf(mx[i], __shfl_xor(mx[i], 4, 64));
    mx[i] = fmaxf(mx[i], __shfl_xor(mx[i], 8, 64));
    sum[i] = __expf(v[0][i] - mx[i]) + __expf(v[1][i] - mx[i])
           + __expf(v[2][i] - mx[i]) + __expf(v[3][i] - mx[i]);
    sum[i] += __shfl_xor(sum[i], 1, 64);
    sum[i] += __shfl_xor(sum[i], 2, 64);
    sum[i] += __shfl_xor(sum[i], 4, 64);
    sum[i] += __shfl_xor(sum[i], 8, 64);
    sum[i] = __logf(sum[i]) + mx[i];       // logsumexp
  }
  #pragma unroll
  for (int i = 0; i < 4; i++) {
    int gr = row0 + wave * 16 + q * 4 + i;
    if (gr < NN) {
      #pragma unroll
      for (int nt = 0; nt < 4; nt++)
        out[(size_t)gr * NC + nt * 16 + m] = v[nt][i] - sum[i];
    }
  }
}

// ---------------- launch ----------------
extern "C" void kernel_launch(void* const* d_in, const int* in_sizes, int n_in,
                              void* d_out, int out_size, void* d_ws, size_t ws_size,
                              hipStream_t stream) {
  const float* x      = (const float*)d_in[0];
  const int*   ei     = (const int*)d_in[1];
  const float* conv_w = (const float*)d_in[3];
  const float* conv_b = (const float*)d_in[4];
  const float* bn_g   = (const float*)d_in[5];
  const float* bn_b   = (const float*)d_in[6];
  const float* bn_m   = (const float*)d_in[7];
  const float* bn_v   = (const float*)d_in[8];
  const float* fc_w   = (const float*)d_in[9];
  const float* fc_b   = (const float*)d_in[10];
  float* out = (float*)d_out;

  const int* srcI = ei;        // edge_index[0]
  const int* dstI = ei + NE;   // edge_index[1]

  // workspace layout (~93 MiB); activation buffers have NN+1 rows (row NN = zeros)
  unsigned short* Xb   = (unsigned short*)d_ws;              // (N+1)*H bf16
  unsigned short* Abuf = Xb + (size_t)(NN + 1) * HF;         // (N+1)*H bf16
  unsigned short* Bbuf = Abuf + (size_t)(NN + 1) * HF;       // (N+1)*H bf16
  int* gcur   = (int*)(Bbuf + (size_t)(NN + 1) * HF);        // NB (+pad) -- counts, memset 0
  int* offs   = gcur + 512;                                  // N+4
  int* deg    = offs + 100004;                               // N+4
  unsigned int* binned = (unsigned int*)(deg + 100004);      // NB*BCAP
  int* csr    = (int*)(binned + (size_t)NB * BCAP);          // NB*BCAP
  unsigned short* wt  = (unsigned short*)(csr + (size_t)NB * BCAP); // 6*16384 bf16 (swizzled)
  unsigned short* wtf = wt + 6 * HF * HF;                    // 64*128 bf16 (swizzled)
  float* sarr = (float*)(wtf + HF * NC);                     // 6*128
  float* tarr = sarr + 6 * HF;                               // 6*128

  hipMemsetAsync(gcur, 0, sizeof(int) * NB, stream);
  prologue_bin<<<3125, 512, 0, stream>>>(x, Xb, conv_w, conv_b, bn_g, bn_b, bn_m, bn_v,
                                         fc_w, wt, wtf, sarr, tarr, gcur,
                                         srcI, dstI, binned);
  build_csr<<<NB, 512, 0, stream>>>(binned, gcur, offs, deg, csr);

  aggregate<<<NN / 4, 256, 0, stream>>>(Xb, offs, deg, csr, Abuf);
  mlp3<<<(NN + 63) / 64, 256, 0, stream>>>(Abuf, Bbuf, wt, sarr, tarr);
  aggregate<<<NN / 4, 256, 0, stream>>>(Bbuf, offs, deg, csr, Abuf);
  mlp3fc<<<(NN + 63) / 64, 256, 0, stream>>>(Abuf, out, wt, sarr, tarr, wtf, fc_b);
}